// Round 5
// baseline (218.680 us; speedup 1.0000x reference)
//
#include <hip/hip_runtime.h>

#define HW 4096
#define NCH 256
#define DIM 128
#define NPROTO 512

typedef __attribute__((ext_vector_type(4))) float f32x4;
typedef __attribute__((ext_vector_type(8))) short s16x8;

__device__ __forceinline__ unsigned short f2bf(float f) {
  union { float f; unsigned u; } v; v.f = f;
  unsigned r = v.u + 0x7fffu + ((v.u >> 16) & 1u);
  return (unsigned short)(r >> 16);
}

// async global->LDS, 16B/lane; LDS dest = wave-uniform base + lane*16
__device__ __forceinline__ void gload_lds16(const void* g, void* l) {
  __builtin_amdgcn_global_load_lds(
      (const __attribute__((address_space(1))) void*)g,
      (__attribute__((address_space(3))) void*)l, 16, 0, 0);
}

// ---------------------------------------------------------------------------
// prep: P -> bf16 chunked Pr[ch][512][32] (+pn2); W -> bf16 row-major [128][256]
// ---------------------------------------------------------------------------
__global__ __launch_bounds__(256) void prep_kernel(const float* __restrict__ P,
                                                   const float* __restrict__ Wm,
                                                   unsigned short* __restrict__ Pr,
                                                   unsigned short* __restrict__ Wbf,
                                                   float* __restrict__ pn2) {
  const int tid = threadIdx.x;
  const int b = blockIdx.x;
  if (b < 8) {
    const int n  = b * 64 + (tid >> 2);
    const int qt = tid & 3;  // d-chunk 32*qt..
    const float* row = P + n * DIM + qt * 32;
    unsigned short* dst = Pr + ((size_t)qt * NPROTO + n) * 32;
    float ssq = 0.f;
#pragma unroll
    for (int u = 0; u < 8; ++u) {
      f32x4 v = *(const f32x4*)(row + 4 * u);
      ssq += v.x * v.x + v.y * v.y + v.z * v.z + v.w * v.w;
      dst[4 * u + 0] = f2bf(v.x);
      dst[4 * u + 1] = f2bf(v.y);
      dst[4 * u + 2] = f2bf(v.z);
      dst[4 * u + 3] = f2bf(v.w);
    }
    ssq += __shfl_xor(ssq, 1);
    ssq += __shfl_xor(ssq, 2);
    if (qt == 0) pn2[n] = ssq;
  } else {
    const int idx = ((b - 8) * 256 + tid) * 16;  // 8*256*16 = 32768 = 128*256
#pragma unroll
    for (int u = 0; u < 4; ++u) {
      f32x4 v = *(const f32x4*)(Wm + idx + 4 * u);
      unsigned short* d = Wbf + idx + 4 * u;
      d[0] = f2bf(v.x); d[1] = f2bf(v.y); d[2] = f2bf(v.z); d[3] = f2bf(v.w);
    }
  }
}

// ---------------------------------------------------------------------------
// fused v2: 32 px x 512 protos per block, 512 thr (8 waves), 2048 blocks.
// Register diet (target <=85 -> 6 waves/SIMD -> 3 blocks/CU):
//   acc[2][4] = 32 regs; P B-frags DIRECT from global (Pr chunked layout =>
//   each j-frag is a contiguous, coalesced 1KB wave load; L2-hot) -- no P LDS.
// Phase 1: K-step 64; W single-buf via gload_lds (proven geometry); x staged
//   by waves 0-3 (pair-packed swizzled b32, proven); per-wave counted vmcnt
//   keeps next x tile in flight; W(it+1) issued after readers-done barrier.
// Phase 1.5: q + bias -> q_s [32][256B] XOR-swizzled bf16 (proven formula).
// Phase 2: 4 chunks, B-frags from global per chunk (sched_barrier fences),
//   exp2 softmax, direct f32x4 stores. LDS total 35072 B.
// ---------------------------------------------------------------------------
__global__ __launch_bounds__(512, 6) void fused_kernel(
    const float* __restrict__ x, const unsigned short* __restrict__ Wbf,
    const float* __restrict__ bias, const unsigned short* __restrict__ Pr,
    const float* __restrict__ pn2, const float* __restrict__ gptr,
    float* __restrict__ out) {
  __shared__ __align__(16) char smem[35072];
  unsigned short* q_s = (unsigned short*)smem;   // [32][128] swizzled (8192)
  char* x_b = smem + 8192;                       // dbuf: 2 x (32 rows x 144B)
  char* wsb = smem + 17408;                      // [128][64] shorts (16384)
  float* red  = (float*)(smem + 33792);          // [8][32]
  float* rmx  = (float*)(smem + 34816);          // [32]
  float* rinv = (float*)(smem + 34944);          // [32]

  const int tid  = threadIdx.x;
  const int p0   = blockIdx.x * 32;
  const int nimg = p0 >> 12;
  const int hw0  = p0 & 4095;
  const int wave = tid >> 6, lane = tid & 63;
  const int l15 = lane & 15, l4 = lane >> 4;
  const int wr = wave >> 2, wc = wave & 3;  // phase-1 tile: px 16wr+, d 32wc+

  // ---------------- phase 1: q = x W^T ----------------
  f32x4 acc1[2];
#pragma unroll
  for (int j = 0; j < 2; ++j)
#pragma unroll
    for (int r = 0; r < 4; ++r) acc1[j][r] = 0.f;

  const float* xb = x + (size_t)nimg * NCH * HW + hw0;
  const int f  = tid & 7;                   // px quad (staging threads)
  const int cp = tid >> 3;                  // ch pair 0..31 (tid<256)
  const int wrow = 8 * wave + (lane >> 3);  // W staging row base
  const int wu   = lane & 7;                // 16B unit in 128B row

  // prologue: W(0) gloads + x(0) -> regs
#pragma unroll
  for (int t = 0; t < 2; ++t) {
    const int row = 64 * t + wrow;
    gload_lds16(Wbf + (size_t)row * NCH + ((wu ^ (row & 7)) << 3),
                wsb + t * 8192 + wave * 1024);
  }
  f32x4 cv0 = {0,0,0,0}, cv1 = {0,0,0,0};
  if (tid < 256) {
    cv0 = *(const f32x4*)(xb + (size_t)(2 * cp + 0) * HW + 4 * f);
    cv1 = *(const f32x4*)(xb + (size_t)(2 * cp + 1) * HW + 4 * f);
  }

#pragma unroll
  for (int it = 0; it < 4; ++it) {
    const int buf = it & 1;
    const int c0n = 64 * (it + 1);
    f32x4 nv0 = cv0, nv1 = cv1;
    if (tid < 256) {
      // pack current x tile (compiler waits cv = x(it) landed)
#pragma unroll
      for (int s = 0; s < 4; ++s) {
        const int row = 4 * f + s;
        unsigned pk = (unsigned)f2bf(cv0[s]) | ((unsigned)f2bf(cv1[s]) << 16);
        *(unsigned*)(x_b + buf * 4608 + row * 144 +
                     ((4 * cp) ^ (((row >> 2) & 7) << 4))) = pk;
      }
      if (it < 3) {  // next x tile -> regs, stays in flight across barrier
        nv0 = *(const f32x4*)(xb + (size_t)(c0n + 2 * cp + 0) * HW + 4 * f);
        nv1 = *(const f32x4*)(xb + (size_t)(c0n + 2 * cp + 1) * HW + 4 * f);
        asm volatile("s_waitcnt vmcnt(2) lgkmcnt(0)" ::: "memory");  // W done
      } else {
        asm volatile("s_waitcnt vmcnt(0) lgkmcnt(0)" ::: "memory");
      }
    } else {
      // waves 4-7: only own W gloads outstanding
      asm volatile("s_waitcnt vmcnt(0)" ::: "memory");
    }
    __builtin_amdgcn_s_barrier();
#pragma unroll
    for (int kc = 0; kc < 64; kc += 32) {
      const int ub = (kc >> 3) + l4;  // 16B unit 0..7
      const int row = 16 * wr + l15;
      s16x8 a = *(const s16x8*)(x_b + buf * 4608 + row * 144 +
                                16 * (ub ^ ((row >> 2) & 7)));
#pragma unroll
      for (int j = 0; j < 2; ++j) {
        s16x8 b = *(const s16x8*)(wsb + (32 * wc + 16 * j + l15) * 128 +
                                  ((ub ^ (l15 & 7)) << 4));
        acc1[j] = __builtin_amdgcn_mfma_f32_16x16x32_bf16(a, b, acc1[j], 0, 0, 0);
      }
    }
    asm volatile("s_waitcnt lgkmcnt(0)" ::: "memory");
    __builtin_amdgcn_s_barrier();  // w_s/x_b readers done
    if (it < 3) {  // W(it+1) into freed w_s; lands by next iter's vmcnt
#pragma unroll
      for (int t = 0; t < 2; ++t) {
        const int row = 64 * t + wrow;
        gload_lds16(Wbf + (size_t)row * NCH + c0n + ((wu ^ (row & 7)) << 3),
                    wsb + t * 8192 + wave * 1024);
      }
    }
    cv0 = nv0; cv1 = nv1;
  }

  // ---------------- phase 1.5: q + bias -> q_s (swizzled bf16) ----------------
  // C/D layout: col = l15 (d within 16-tile), row = 4*l4 + r (px)
#pragma unroll
  for (int j = 0; j < 2; ++j) {
    const int d = 32 * wc + 16 * j + l15;
    const float bv = bias[d];
    const int u  = d >> 3;
    const int d7 = d & 7;
    const int pxb = 16 * wr + 4 * l4;
#pragma unroll
    for (int r = 0; r < 4; ++r) {
      const int px = pxb + r;
      q_s[px * 128 + ((u ^ (px & 7)) << 3) + d7] = f2bf(acc1[j][r] + bv);
    }
  }

  // ---------------- phase 2: attn, B-frags direct from global ----------------
  f32x4 acc[2][4];
#pragma unroll
  for (int i = 0; i < 2; ++i)
#pragma unroll
    for (int j = 0; j < 4; ++j)
#pragma unroll
      for (int r = 0; r < 4; ++r) acc[i][j][r] = 0.f;

  // chunk-0 B frags issued before the barrier (flight under q_s writes)
  s16x8 bq[4];
#pragma unroll
  for (int j = 0; j < 4; ++j)
    bq[j] = *(const s16x8*)(Pr + (size_t)(64 * wave + 16 * j + l15) * 32 + 8 * l4);
  __syncthreads();  // q_s visible to all waves

#pragma unroll
  for (int ch = 0; ch < 4; ++ch) {
    s16x8 afr[2];
#pragma unroll
    for (int i = 0; i < 2; ++i) {
      const int px = 16 * i + l15;
      afr[i] = *(const s16x8*)&q_s[px * 128 + (((4 * ch + l4) ^ (px & 7)) << 3)];
    }
#pragma unroll
    for (int j = 0; j < 4; ++j)
#pragma unroll
      for (int i = 0; i < 2; ++i)
        acc[i][j] = __builtin_amdgcn_mfma_f32_16x16x32_bf16(afr[i], bq[j], acc[i][j], 0, 0, 0);
    if (ch < 3) {  // next chunk's frags (L2-hot, coalesced 1KB/wave-load)
      __builtin_amdgcn_sched_barrier(0);
#pragma unroll
      for (int j = 0; j < 4; ++j)
        bq[j] = *(const s16x8*)(Pr + (size_t)((ch + 1) * NPROTO + 64 * wave + 16 * j + l15) * 32 + 8 * l4);
    }
  }

  // softmax over 512 protos (exp2 domain; qn2 row-constant cancels)
  const float g2  = fabsf(gptr[0]) * 1.44269504088896340736f;
  const float tg2 = 2.f * g2;
  float cj[4];
#pragma unroll
  for (int j = 0; j < 4; ++j) cj[j] = g2 * pn2[64 * wave + 16 * j + l15];

#pragma unroll
  for (int i = 0; i < 2; ++i)
#pragma unroll
    for (int r = 0; r < 4; ++r) {
      float m = -1e30f;
#pragma unroll
      for (int j = 0; j < 4; ++j) {
        float lv = fmaf(acc[i][j][r], tg2, -cj[j]);
        acc[i][j][r] = lv;
        m = fmaxf(m, lv);
      }
#pragma unroll
      for (int s = 1; s < 16; s <<= 1) m = fmaxf(m, __shfl_xor(m, s));
      if (l15 == 0) red[wave * 32 + 16 * i + 4 * l4 + r] = m;
    }
  __syncthreads();
  if (tid < 32) {
    float M = red[tid];
#pragma unroll
    for (int w = 1; w < 8; ++w) M = fmaxf(M, red[w * 32 + tid]);
    rmx[tid] = M;
  }
  __syncthreads();

#pragma unroll
  for (int i = 0; i < 2; ++i) {
    const f32x4 Mi = *(const f32x4*)&rmx[16 * i + 4 * l4];
#pragma unroll
    for (int r = 0; r < 4; ++r) {
      float s = 0.f;
#pragma unroll
      for (int j = 0; j < 4; ++j) {
        float e = exp2f(acc[i][j][r] - Mi[r]);
        acc[i][j][r] = e;
        s += e;
      }
#pragma unroll
      for (int t = 1; t < 16; t <<= 1) s += __shfl_xor(s, t);
      if (l15 == 0) red[wave * 32 + 16 * i + 4 * l4 + r] = s;
    }
  }
  __syncthreads();
  if (tid < 32) {
    float S = 0.f;
#pragma unroll
    for (int w = 0; w < 8; ++w) S += red[w * 32 + tid];
    rinv[tid] = 1.f / S;
  }
  __syncthreads();

  // direct stores: f32x4 over r = 4 consecutive px
  float* ob = out + (size_t)nimg * NPROTO * HW + hw0;
#pragma unroll
  for (int i = 0; i < 2; ++i) {
    const f32x4 iv = *(const f32x4*)&rinv[16 * i + 4 * l4];
    const int px = 16 * i + 4 * l4;
#pragma unroll
    for (int j = 0; j < 4; ++j) {
      const int k = 64 * wave + 16 * j + l15;
      f32x4 o = acc[i][j] * iv;
      *(f32x4*)(ob + (size_t)k * HW + px) = o;
    }
  }
}

extern "C" void kernel_launch(void* const* d_in, const int* in_sizes, int n_in,
                              void* d_out, int out_size, void* d_ws, size_t ws_size,
                              hipStream_t stream) {
  const float* x     = (const float*)d_in[0];
  const float* Wm    = (const float*)d_in[1];
  const float* bias  = (const float*)d_in[2];
  const float* prot  = (const float*)d_in[3];
  const float* gamma = (const float*)d_in[4];
  float* out = (float*)d_out;

  // workspace: Pr chunked bf16 (128 KiB) | pn2 (2 KiB) | W bf16 (64 KiB)
  unsigned short* Pr_w  = (unsigned short*)d_ws;
  float*          pn2_w = (float*)((char*)d_ws + 131072);
  unsigned short* W_ws  = (unsigned short*)((char*)d_ws + 131072 + 2048);

  prep_kernel<<<16, 256, 0, stream>>>(prot, Wm, Pr_w, W_ws, pn2_w);
  fused_kernel<<<2048, 512, 0, stream>>>(x, W_ws, bias, Pr_w, pn2_w, gamma, out);
}